// Round 7
// baseline (697.013 us; speedup 1.0000x reference)
//
#include <hip/hip_runtime.h>

typedef unsigned short u16;
typedef __attribute__((ext_vector_type(8))) short short8;
typedef __attribute__((ext_vector_type(4))) float floatx4;
typedef __attribute__((ext_vector_type(4))) unsigned int uintx4;

#define B_    16
#define C_    512
#define N_    4096
#define NH_   8
#define HD_   64
#define MQKV  1536
#define NSPL  8

union V16 { uintx4 u; u16 s[8]; short8 h; };

__device__ inline u16 f2bf(float f) {
  union { float f; unsigned int i; } c; c.f = f;
  unsigned int i = c.i;
  return (u16)((i + 0x7FFFu + ((i >> 16) & 1u)) >> 16);
}

// async global->LDS, 16B per lane; LDS dest must be wave-uniform-base + lane*16
__device__ __forceinline__ void gld16(const u16* g, u16* l) {
  __builtin_amdgcn_global_load_lds(
      (const __attribute__((address_space(1))) unsigned int*)g,
      (__attribute__((address_space(3))) unsigned int*)l, 16, 0, 0);
}

// ---------------- Kernel 1: GroupNorm stats -> per-(b,c) affine (f32 in) ----------------
__global__ __launch_bounds__(256) void gn_stats(const float* __restrict__ x,
    const float* __restrict__ gamma, const float* __restrict__ beta,
    float* __restrict__ s_arr, float* __restrict__ t_arr) {
  int b = blockIdx.x >> 5, g = blockIdx.x & 31;
  const floatx4* p = (const floatx4*)(x + (size_t)(b * C_ + g * 16) * N_);
  int tid = threadIdx.x;
  float sum = 0.f, ssq = 0.f;
  for (int it = 0; it < 64; ++it) {
    floatx4 v = p[tid + it * 256];
#pragma unroll
    for (int j = 0; j < 4; ++j) { float f = v[j]; sum += f; ssq += f * f; }
  }
#pragma unroll
  for (int off = 32; off > 0; off >>= 1) {
    sum += __shfl_down(sum, off);
    ssq += __shfl_down(ssq, off);
  }
  __shared__ float red[8];
  __shared__ float mv[2];
  int lane = tid & 63, wid = tid >> 6;
  if (lane == 0) { red[wid] = sum; red[wid + 4] = ssq; }
  __syncthreads();
  if (tid == 0) {
    float s = red[0] + red[1] + red[2] + red[3];
    float q = red[4] + red[5] + red[6] + red[7];
    float mean = s * (1.f / 65536.f);
    float var  = q * (1.f / 65536.f) - mean * mean;
    mv[0] = mean; mv[1] = rsqrtf(var + 1e-5f);
  }
  __syncthreads();
  if (tid < 16) {
    int c = g * 16 + tid;
    float ga = gamma[c], be = beta[c];
    float mean = mv[0], rstd = mv[1];
    s_arr[b * C_ + c] = ga * rstd;
    t_arr[b * C_ + c] = be - mean * rstd * ga;
  }
}

// ---------------- Kernel 1b: f32 -> bf16 convert (weights, one-time) ----------------
__global__ __launch_bounds__(256) void cvt_bf16(const float* __restrict__ src,
                                                u16* __restrict__ dst) {
  int i = blockIdx.x * 256 + threadIdx.x;
  const floatx4* s4 = (const floatx4*)src;
  floatx4 a = s4[2 * i], b = s4[2 * i + 1];
  V16 v;
#pragma unroll
  for (int j = 0; j < 4; ++j) { v.s[j] = f2bf(a[j]); v.s[4 + j] = f2bf(b[j]); }
  ((uintx4*)dst)[i] = v.u;
}

// ---- Kernel 1c: GN-apply + transpose: x[b][c][n] f32 -> xt[b][n][c] bf16 ----
__global__ __launch_bounds__(256) void gn_apply_t(const float* __restrict__ x,
    const float* __restrict__ s_arr, const float* __restrict__ t_arr,
    u16* __restrict__ xt, int b0) {
  __shared__ float T[64][65];
  int bz = blockIdx.z, gb = b0 + bz;
  int n0 = blockIdx.x * 64, c0 = blockIdx.y * 64;
  int tid = threadIdx.x;
  int cl = tid >> 4;
  int nl = (tid & 15) * 4;
  const float* xb = x + (size_t)bz * C_ * N_;
#pragma unroll
  for (int ci = 0; ci < 4; ++ci) {
    int c = c0 + cl + ci * 16;
    float s = s_arr[gb * C_ + c], t = t_arr[gb * C_ + c];
    floatx4 v = *(const floatx4*)(xb + (size_t)c * N_ + n0 + nl);
#pragma unroll
    for (int j = 0; j < 4; ++j) T[cl + ci * 16][nl + j] = s * v[j] + t;
  }
  __syncthreads();
  int n = tid >> 2, cc = (tid & 3) * 16;
  V16 a, b;
#pragma unroll
  for (int j = 0; j < 8; ++j) a.s[j] = f2bf(T[cc + j][n]);
#pragma unroll
  for (int j = 0; j < 8; ++j) b.s[j] = f2bf(T[cc + 8 + j][n]);
  uintx4* dst = (uintx4*)(xt + (size_t)bz * N_ * C_ + (size_t)(n0 + n) * C_ + c0 + cc);
  dst[0] = a.u; dst[1] = b.u;
}

// ------- Kernel 2b: 256x256-tile GEMM, bf16 out: out[bz][m][n] = A[m][k]*B[bz][n][k]^T ----
// 512 thr / 8 waves (2Mx4N), LDS 128KB [buf][A|B][ks][256][32], K-half counted-vmcnt pipe.
__global__ __launch_bounds__(512, 2) void gemm_bt2(
    const u16* __restrict__ A, const u16* __restrict__ Bm,
    const float* __restrict__ bias, u16* __restrict__ outp, int M) {
  __shared__ alignas(16) u16 smem[65536];   // 128 KB
  int bz = blockIdx.z;
  int m0 = blockIdx.y * 256, n0 = blockIdx.x * 256;
  int tid = threadIdx.x, lane = tid & 63, wid = tid >> 6;
  int quad = lane >> 4, l15 = lane & 15;
  int wm = (wid >> 2) * 128, wn = (wid & 3) * 64;
  int r0 = tid >> 2, sc = tid & 3;   // staging: row base, 16B-chunk (4 chunks per 32-col half)
  const u16* Bb = Bm + (size_t)bz * ((size_t)N_ * C_);
  floatx4 acc[8][4];
#pragma unroll
  for (int i = 0; i < 8; ++i)
#pragma unroll
    for (int j = 0; j < 4; ++j) acc[i][j] = (floatx4)0.f;

  // stage one K-half (ks) of tile kt into buffer buf: 4 gld16/thread-pair (A+B, 2 rows)
  auto stageK = [&](int kt, int ks, int buf) {
    u16* Adst = smem + buf * 32768 + ks * 8192;
    u16* Bdst = Adst + 16384;
    int kb = kt * 64 + ks * 32;
#pragma unroll
    for (int ld = 0; ld < 2; ++ld) {
      int rr = r0 + ld * 128;
      int cc = sc ^ ((rr >> 1) & 3);   // source-side XOR pre-swizzle (key (row>>1)&3)
      gld16(A  + (size_t)(m0 + rr) * C_ + kb + cc * 8, Adst + rr * 32 + sc * 8);
      gld16(Bb + (size_t)(n0 + rr) * C_ + kb + cc * 8, Bdst + rr * 32 + sc * 8);
    }
  };
  // compute one K-half (32 MFMA/wave) from buffer buf
  auto computeKS = [&](int ks, int buf) {
    const u16* As = smem + buf * 32768 + ks * 8192;
    const u16* Bs = As + 16384;
    short8 af[8], bf[4];
#pragma unroll
    for (int mi = 0; mi < 8; ++mi) {
      int row = wm + mi * 16 + l15;
      af[mi] = *(const short8*)&As[row * 32 + (quad ^ ((row >> 1) & 3)) * 8];
    }
#pragma unroll
    for (int ni = 0; ni < 4; ++ni) {
      int row = wn + ni * 16 + l15;
      bf[ni] = *(const short8*)&Bs[row * 32 + (quad ^ ((row >> 1) & 3)) * 8];
    }
#pragma unroll
    for (int mi = 0; mi < 8; ++mi)
#pragma unroll
      for (int ni = 0; ni < 4; ++ni)
        acc[mi][ni] = __builtin_amdgcn_mfma_f32_16x16x32_bf16(af[mi], bf[ni], acc[mi][ni], 0, 0, 0);
  };

  // prologue: stage tile 0 (k0 then k1); require k0 landed (k1 may stay in flight)
  stageK(0, 0, 0);
  stageK(0, 1, 0);
  asm volatile("s_waitcnt vmcnt(4)" ::: "memory");
  __builtin_amdgcn_s_barrier();
  int cur = 0;
  for (int kt = 0; kt < 8; ++kt) {
    if (kt < 7) stageK(kt + 1, 0, cur ^ 1);       // +4 loads
    computeKS(0, cur);                            // cur.k0 guaranteed by previous wait
    if (kt < 7) stageK(kt + 1, 1, cur ^ 1);       // +4 loads
    if (kt < 7) asm volatile("s_waitcnt vmcnt(4)" ::: "memory"); // all but newest 4 landed
    else        asm volatile("s_waitcnt vmcnt(0)" ::: "memory"); // final drain
    __builtin_amdgcn_s_barrier();                 // cur.k1 (and next.k0) globally in LDS
    computeKS(1, cur);
    __builtin_amdgcn_s_barrier();                 // all waves done reading cur before overwrite
    cur ^= 1;
  }
  // ---- epilogue: 256x256 u16 tile in smem (exact reuse), XOR-swizzled, 16B stores ----
  __syncthreads();
  u16* E = smem;
#pragma unroll
  for (int mi = 0; mi < 8; ++mi)
#pragma unroll
    for (int ni = 0; ni < 4; ++ni)
#pragma unroll
      for (int r = 0; r < 4; ++r) {
        int row = wm + mi * 16 + quad * 4 + r;
        int col = wn + ni * 16 + l15;
        int ch = col >> 3;                         // 0..31
        int cs = (ch & ~7) | ((ch & 7) ^ (row & 7));
        E[row * 256 + cs * 8 + (col & 7)] = f2bf(acc[mi][ni][r] + bias[m0 + row]);
      }
  __syncthreads();
  int row = tid >> 1, half = tid & 1;
  u16* orow = outp + ((size_t)bz * M + m0 + row) * N_ + n0 + half * 128;
#pragma unroll
  for (int k = 0; k < 16; ++k) {
    int ch = half * 16 + k;
    int cs = (ch & ~7) | ((ch & 7) ^ (row & 7));
    *(uintx4*)(orow + k * 8) = *(const uintx4*)&E[row * 256 + cs * 8];
  }
}

// ------- Kernel 2/5: 128x128-tile GEMM (f32 path w/ bias+resid) — proj only ----
__global__ __launch_bounds__(256) void gemm_bt(
    const u16* __restrict__ A, const u16* __restrict__ Bm,
    const float* __restrict__ bias, const float* __restrict__ resid,
    void* __restrict__ outv, int M, int doRes, int outF32) {
  __shared__ alignas(16) u16 smem[2 * 2 * 128 * 64];   // [buf][As|Bs]; epilogue reuses
  int bz = blockIdx.z;
  int m0 = blockIdx.y * 128, n0 = blockIdx.x * 128;
  int tid = threadIdx.x, lane = tid & 63, wid = tid >> 6;
  int quad = lane >> 4, l15 = lane & 15;
  int wm = (wid >> 1) * 64, wn = (wid & 1) * 64;
  int sr = tid >> 3, sc = tid & 7;
  const u16* Bb = Bm + (size_t)bz * ((size_t)N_ * C_);
  floatx4 acc[4][4];
#pragma unroll
  for (int i = 0; i < 4; ++i)
#pragma unroll
    for (int j = 0; j < 4; ++j) acc[i][j] = (floatx4)0.f;

  auto stage = [&](int kt, int p) {
    u16* As = smem + p * 16384;
    u16* Bs = As + 8192;
#pragma unroll
    for (int i = 0; i < 4; ++i) {
      int rr = sr + i * 32;
      int cc = sc ^ (rr & 7);
      gld16(A  + (size_t)(m0 + rr) * C_ + kt * 64 + cc * 8, &As[rr * 64 + sc * 8]);
      gld16(Bb + (size_t)(n0 + rr) * C_ + kt * 64 + cc * 8, &Bs[rr * 64 + sc * 8]);
    }
  };

  stage(0, 0);
  asm volatile("s_waitcnt vmcnt(0)" ::: "memory");
  __builtin_amdgcn_s_barrier();
  int cur = 0;
  for (int kt = 0; kt < 8; ++kt) {
    if (kt < 7) stage(kt + 1, cur ^ 1);
    const u16* As = smem + cur * 16384;
    const u16* Bs = As + 8192;
#pragma unroll
    for (int ks = 0; ks < 2; ++ks) {
      short8 af[4], bf8[4];
#pragma unroll
      for (int mi = 0; mi < 4; ++mi) {
        int row = wm + mi * 16 + l15;
        int kc = (ks * 4 + quad) ^ (row & 7);
        af[mi] = *(const short8*)&As[row * 64 + kc * 8];
      }
#pragma unroll
      for (int ni = 0; ni < 4; ++ni) {
        int row = wn + ni * 16 + l15;
        int kc = (ks * 4 + quad) ^ (row & 7);
        bf8[ni] = *(const short8*)&Bs[row * 64 + kc * 8];
      }
#pragma unroll
      for (int mi = 0; mi < 4; ++mi)
#pragma unroll
        for (int ni = 0; ni < 4; ++ni)
          acc[mi][ni] = __builtin_amdgcn_mfma_f32_16x16x32_bf16(af[mi], bf8[ni], acc[mi][ni], 0, 0, 0);
    }
    asm volatile("s_waitcnt vmcnt(0)" ::: "memory");
    __builtin_amdgcn_s_barrier();
    cur ^= 1;
  }
  if (!outF32) {
    u16* E = smem;
#pragma unroll
    for (int mi = 0; mi < 4; ++mi)
#pragma unroll
      for (int ni = 0; ni < 4; ++ni)
#pragma unroll
        for (int r = 0; r < 4; ++r) {
          int row = wm + mi * 16 + quad * 4 + r;
          int col = wn + ni * 16 + l15;
          int ch = col >> 3;
          int cs = (ch & 8) | ((ch & 7) ^ (row & 7));
          E[row * 128 + cs * 8 + (col & 7)] = f2bf(acc[mi][ni][r] + bias[m0 + row]);
        }
    __syncthreads();
    int row = tid >> 1, half = tid & 1;
    u16* orow = (u16*)outv + ((size_t)bz * M + m0 + row) * N_ + n0 + half * 64;
#pragma unroll
    for (int k = 0; k < 8; ++k) {
      int cs = (half * 8) | (k ^ (row & 7));
      *(uintx4*)(orow + k * 8) = *(const uintx4*)&E[row * 128 + cs * 8];
    }
  } else {
    float* E = (float*)smem;
#pragma unroll
    for (int p = 0; p < 2; ++p) {
#pragma unroll
      for (int q = 0; q < 2; ++q)
#pragma unroll
        for (int ni = 0; ni < 4; ++ni)
#pragma unroll
          for (int r = 0; r < 4; ++r) {
            int mi = p * 2 + q;
            int lr = (wid >> 1) * 32 + q * 16 + quad * 4 + r;
            int col = wn + ni * 16 + l15;
            int ch = col >> 2;
            int cs = (ch & ~7) | ((ch & 7) ^ (lr & 7));
            E[lr * 128 + cs * 4 + (col & 3)] =
                acc[mi][ni][r] + bias[m0 + wm + mi * 16 + quad * 4 + r];
          }
      __syncthreads();
      int lr = tid >> 2, qt = tid & 3;
      int o = m0 + (lr >> 5) * 64 + p * 32 + (lr & 31);
      size_t obase = ((size_t)bz * M + o) * N_ + n0 + qt * 4;
#pragma unroll
      for (int k = 0; k < 8; ++k) {
        int ch = k * 4 + qt;
        int cs = (ch & ~7) | ((ch & 7) ^ (lr & 7));
        floatx4 v = *(const floatx4*)&E[lr * 128 + cs * 4];
        if (doRes) v += *(const floatx4*)(resid + obase + (size_t)k * 16);
        *(floatx4*)((float*)outv + obase + (size_t)k * 16) = v;
      }
      if (p == 0) __syncthreads();
    }
  }
}

// ---- Kernel 3a: partial S over an N-slice -> spart[p][bh][64][64] f32 ----
__global__ __launch_bounds__(256) void qk_partial(const u16* __restrict__ qkv,
    float* __restrict__ spart, int nbh) {
  int h = blockIdx.x, bz = blockIdx.y, p = blockIdx.z;
  const u16* qb = qkv + ((size_t)bz * MQKV + h * HD_) * N_;
  const u16* kb = qkv + ((size_t)bz * MQKV + C_ + h * HD_) * N_;
  int tid = threadIdx.x, lane = tid & 63, wid = tid >> 6;
  int quad = lane >> 4, l15 = lane & 15;
  floatx4 acc[4][4];
#pragma unroll
  for (int i = 0; i < 4; ++i)
#pragma unroll
    for (int j = 0; j < 4; ++j) acc[i][j] = (floatx4)0.f;

  for (int ks = 0; ks < 4; ++ks) {
    int n = p * 512 + wid * 128 + ks * 32 + quad * 8;
    short8 af[4], bf8[4];
#pragma unroll
    for (int mi = 0; mi < 4; ++mi)
      af[mi] = *(const short8*)(qb + (size_t)(mi * 16 + l15) * N_ + n);
#pragma unroll
    for (int ni = 0; ni < 4; ++ni)
      bf8[ni] = *(const short8*)(kb + (size_t)(ni * 16 + l15) * N_ + n);
#pragma unroll
    for (int mi = 0; mi < 4; ++mi)
#pragma unroll
      for (int ni = 0; ni < 4; ++ni)
        acc[mi][ni] = __builtin_amdgcn_mfma_f32_16x16x32_bf16(af[mi], bf8[ni], acc[mi][ni], 0, 0, 0);
  }
  __shared__ float S[64 * 68];
  for (int i = tid; i < 64 * 68; i += 256) S[i] = 0.f;
  __syncthreads();
#pragma unroll
  for (int mi = 0; mi < 4; ++mi)
#pragma unroll
    for (int ni = 0; ni < 4; ++ni)
#pragma unroll
      for (int r = 0; r < 4; ++r)
        atomicAdd(&S[(mi * 16 + quad * 4 + r) * 68 + ni * 16 + l15], acc[mi][ni][r]);
  __syncthreads();
  int bh = bz * NH_ + h;
  float* dst = spart + ((size_t)p * nbh + bh) * 4096 + tid * 16;
  int row = tid >> 2, c0 = (tid & 3) * 16;
#pragma unroll
  for (int j = 0; j < 4; ++j)
    *(floatx4*)(dst + j * 4) = *(const floatx4*)&S[row * 68 + c0 + j * 4];
}

// ---- Kernel 3b: sum partials + row softmax (one lane per row) ----
__global__ __launch_bounds__(64) void softmax_rows(const float* __restrict__ spart,
    float* __restrict__ attn, int nbh) {
  int bh = blockIdx.x, c = threadIdx.x;
  const float* sp = spart + (size_t)bh * 4096 + c * 64;
  floatx4 row4[16];
#pragma unroll
  for (int j = 0; j < 16; ++j) row4[j] = *(const floatx4*)(sp + j * 4);
#pragma unroll
  for (int p = 1; p < NSPL; ++p) {
    const float* spp = sp + (size_t)p * nbh * 4096;
#pragma unroll
    for (int j = 0; j < 16; ++j) row4[j] += *(const floatx4*)(spp + j * 4);
  }
  float mx = -1e30f;
#pragma unroll
  for (int j = 0; j < 16; ++j)
#pragma unroll
    for (int e = 0; e < 4; ++e) mx = fmaxf(mx, row4[j][e]);
  float sum = 0.f;
#pragma unroll
  for (int j = 0; j < 16; ++j)
#pragma unroll
    for (int e = 0; e < 4; ++e) {
      float ev = __expf((row4[j][e] - mx) * 0.125f);
      row4[j][e] = ev; sum += ev;
    }
  float inv = 1.f / sum;
  float* dst = attn + (size_t)bh * 4096 + c * 64;
#pragma unroll
  for (int j = 0; j < 16; ++j) *(floatx4*)(dst + j * 4) = row4[j] * inv;
}

// ------- Kernel 4: O = attn * v, output TRANSPOSED ot[bz][n][c] bf16 (c = h*64+hd) -----
__global__ __launch_bounds__(256) void pv_kernel(const float* __restrict__ attn,
    const u16* __restrict__ qkv, u16* __restrict__ ot) {
  int nt = blockIdx.x, h = blockIdx.y, bz = blockIdx.z;
  int n0 = nt * 256;
  const u16* vb = qkv + ((size_t)bz * MQKV + 2 * C_ + h * HD_) * N_;
  __shared__ alignas(16) u16 Ps[64 * 72];
  __shared__ alignas(16) u16 Vs[256 * 72];
  int tid = threadIdx.x, lane = tid & 63, wid = tid >> 6;
  int quad = lane >> 4, l15 = lane & 15;
  const float* ab = attn + (size_t)(bz * NH_ + h) * 4096;
#pragma unroll
  for (int i = 0; i < 16; ++i) {
    int idx = tid + i * 256;
    int row = idx >> 6, col = idx & 63;
    Ps[row * 72 + col] = f2bf(ab[idx]);
  }
#pragma unroll
  for (int i = 0; i < 8; ++i) {
    int l = tid + i * 256;
    int ch = l >> 5, n8 = (l & 31) * 8;
    V16 v; v.u = *(const uintx4*)(vb + (size_t)ch * N_ + n0 + n8);
    int chunk = ch >> 3, clo = ch & 7;
#pragma unroll
    for (int j = 0; j < 8; ++j) {
      int nl = n8 + j;
      Vs[nl * 72 + (chunk ^ ((nl >> 3) & 7)) * 8 + clo] = v.s[j];
    }
  }
  __syncthreads();
  floatx4 acc[4][4];
#pragma unroll
  for (int i = 0; i < 4; ++i)
#pragma unroll
    for (int j = 0; j < 4; ++j) acc[i][j] = (floatx4)0.f;
#pragma unroll
  for (int ks = 0; ks < 2; ++ks) {
    short8 af[4], bf8[4];
    int ko = ks * 32 + quad * 8;
#pragma unroll
    for (int mi = 0; mi < 4; ++mi)
      af[mi] = *(const short8*)&Ps[(mi * 16 + l15) * 72 + ko];
    int chunk = ks * 4 + quad;
#pragma unroll
    for (int ni = 0; ni < 4; ++ni) {
      int nl = wid * 64 + ni * 16 + l15;
      bf8[ni] = *(const short8*)&Vs[nl * 72 + (chunk ^ ((nl >> 3) & 7)) * 8];
    }
#pragma unroll
    for (int mi = 0; mi < 4; ++mi)
#pragma unroll
      for (int ni = 0; ni < 4; ++ni)
        acc[mi][ni] = __builtin_amdgcn_mfma_f32_16x16x32_bf16(af[mi], bf8[ni], acc[mi][ni], 0, 0, 0);
  }
  __syncthreads();
  u16* Ls = Vs;
#pragma unroll
  for (int mi = 0; mi < 4; ++mi)
#pragma unroll
    for (int ni = 0; ni < 4; ++ni)
#pragma unroll
      for (int r = 0; r < 4; ++r) {
        int n  = wid * 64 + ni * 16 + l15;
        int hd = mi * 16 + quad * 4 + r;
        Ls[n * 64 + (((hd >> 3) ^ (n & 7)) * 8) + (hd & 7)] = f2bf(acc[mi][ni][r]);
      }
  __syncthreads();
  uintx4* dst = (uintx4*)(ot + ((size_t)bz * N_ + n0 + tid) * C_ + h * HD_);
#pragma unroll
  for (int k = 0; k < 8; ++k) {
    int kc = k ^ (tid & 7);
    dst[k] = *(const uintx4*)&Ls[tid * 64 + kc * 8];
  }
}

extern "C" void kernel_launch(void* const* d_in, const int* in_sizes, int n_in,
                              void* d_out, int out_size, void* d_ws, size_t ws_size,
                              hipStream_t stream) {
  const float* x      = (const float*)d_in[0];
  const float* gamma  = (const float*)d_in[1];
  const float* beta   = (const float*)d_in[2];
  const float* w_qkv  = (const float*)d_in[3];
  const float* b_qkv  = (const float*)d_in[4];
  const float* w_proj = (const float*)d_in[5];
  const float* b_proj = (const float*)d_in[6];
  float* out = (float*)d_out;

  const size_t fixed = (size_t)2 * B_ * C_ * 4 + (size_t)(MQKV + C_) * C_ * 2;
  const size_t per_batch = (size_t)NH_ * 64 * 64 * 4 + (size_t)N_ * C_ * 2 + (size_t)MQKV * N_ * 2;
  int Bc = 16;
  while (Bc > 1 && fixed + (size_t)Bc * per_batch > ws_size) Bc >>= 1;

  float* s_arr = (float*)d_ws;
  float* t_arr = s_arr + B_ * C_;
  u16* wq = (u16*)(t_arr + B_ * C_);
  u16* wp = wq + MQKV * C_;
  float* attn = (float*)(wp + C_ * C_);
  u16* xt  = (u16*)(attn + (size_t)Bc * NH_ * 64 * 64);
  u16* qkv = xt + (size_t)Bc * N_ * C_;
  float* spart = (float*)xt;  // xt dead between QKV gemm and pv

  gn_stats<<<dim3(B_ * 32), dim3(256), 0, stream>>>(x, gamma, beta, s_arr, t_arr);
  cvt_bf16<<<dim3(MQKV * C_ / 2048), dim3(256), 0, stream>>>(w_qkv, wq);
  cvt_bf16<<<dim3(C_ * C_ / 2048), dim3(256), 0, stream>>>(w_proj, wp);

  for (int b0 = 0; b0 < B_; b0 += Bc) {
    int nbh = Bc * NH_;
    gn_apply_t<<<dim3(N_ / 64, C_ / 64, Bc), dim3(256), 0, stream>>>(
        x + (size_t)b0 * C_ * N_, s_arr, t_arr, xt, b0);
    gemm_bt2<<<dim3(16, 6, Bc), dim3(512), 0, stream>>>(
        wq, xt, b_qkv, qkv, MQKV);
    qk_partial<<<dim3(NH_, Bc, NSPL), dim3(256), 0, stream>>>(qkv, spart, nbh);
    softmax_rows<<<dim3(nbh), dim3(64), 0, stream>>>(spart, attn, nbh);
    pv_kernel<<<dim3(16, NH_, Bc), dim3(256), 0, stream>>>(attn, qkv, xt);  // xt := o_t
    gemm_bt<<<dim3(32, 4, Bc), dim3(256), 0, stream>>>(
        wp, xt, b_proj, x + (size_t)b0 * C_ * N_, out + (size_t)b0 * C_ * N_, C_, 1, 1);
  }
}

// Round 8
// 692.367 us; speedup vs baseline: 1.0067x; 1.0067x over previous
//
#include <hip/hip_runtime.h>

typedef unsigned short u16;
typedef __attribute__((ext_vector_type(8))) short short8;
typedef __attribute__((ext_vector_type(4))) float floatx4;
typedef __attribute__((ext_vector_type(4))) unsigned int uintx4;

#define B_    16
#define C_    512
#define N_    4096
#define NH_   8
#define HD_   64
#define MQKV  1536
#define NSPL  8

union V16 { uintx4 u; u16 s[8]; short8 h; };

__device__ inline u16 f2bf(float f) {
  union { float f; unsigned int i; } c; c.f = f;
  unsigned int i = c.i;
  return (u16)((i + 0x7FFFu + ((i >> 16) & 1u)) >> 16);
}

// async global->LDS, 16B per lane; LDS dest must be wave-uniform-base + lane*16
__device__ __forceinline__ void gld16(const u16* g, u16* l) {
  __builtin_amdgcn_global_load_lds(
      (const __attribute__((address_space(1))) unsigned int*)g,
      (__attribute__((address_space(3))) unsigned int*)l, 16, 0, 0);
}

// ---- Kernel 1: GroupNorm stats + transpose-cast in ONE x pass ----
// Writes xtg[bl][g][n][16] bf16 (raw x, NO affine — GN folded into weights),
// and s_arr/t_arr per (gb,c). grid (Bc*32), block 256.
__global__ __launch_bounds__(256) void gn_stats_t(const float* __restrict__ x,
    const float* __restrict__ gamma, const float* __restrict__ beta,
    float* __restrict__ s_arr, float* __restrict__ t_arr,
    u16* __restrict__ xtg, int b0) {
  __shared__ float T[16][256];   // 16 KB tile
  int bl = blockIdx.x >> 5, g = blockIdx.x & 31;
  int gb = b0 + bl;
  int tid = threadIdx.x;
  const float* xb = x + ((size_t)bl * C_ + g * 16) * N_;
  u16* xd = xtg + ((size_t)bl * 32 + g) * N_ * 16;
  float sum = 0.f, ssq = 0.f;
  for (int t8 = 0; t8 < 16; ++t8) {     // 16 n-tiles of 256
    int nb = t8 * 256;
#pragma unroll
    for (int i = 0; i < 4; ++i) {
      int idx = tid + i * 256;          // 0..1023
      int row = idx >> 6, col4 = idx & 63;
      floatx4 v = *(const floatx4*)(xb + (size_t)row * N_ + nb + col4 * 4);
#pragma unroll
      for (int j = 0; j < 4; ++j) { float f = v[j]; sum += f; ssq += f * f; }
      *(floatx4*)&T[row][col4 * 4] = v;
    }
    __syncthreads();
    // transposed write: thread -> n = nb+tid, 16 chans = 32B contiguous
    V16 a, b;
#pragma unroll
    for (int j = 0; j < 8; ++j) a.s[j] = f2bf(T[j][tid]);
#pragma unroll
    for (int j = 0; j < 8; ++j) b.s[j] = f2bf(T[8 + j][tid]);
    uintx4* dst = (uintx4*)(xd + (size_t)(nb + tid) * 16);
    dst[0] = a.u; dst[1] = b.u;
    __syncthreads();
  }
#pragma unroll
  for (int off = 32; off > 0; off >>= 1) {
    sum += __shfl_down(sum, off);
    ssq += __shfl_down(ssq, off);
  }
  __shared__ float red[8];
  __shared__ float mv[2];
  int lane = tid & 63, wid = tid >> 6;
  if (lane == 0) { red[wid] = sum; red[wid + 4] = ssq; }
  __syncthreads();
  if (tid == 0) {
    float s = red[0] + red[1] + red[2] + red[3];
    float q = red[4] + red[5] + red[6] + red[7];
    float mean = s * (1.f / 65536.f);
    float var  = q * (1.f / 65536.f) - mean * mean;
    mv[0] = mean; mv[1] = rsqrtf(var + 1e-5f);
  }
  __syncthreads();
  if (tid < 16) {
    int c = g * 16 + tid;
    float ga = gamma[c], be = beta[c];
    float mean = mv[0], rstd = mv[1];
    s_arr[gb * C_ + c] = ga * rstd;
    t_arr[gb * C_ + c] = be - mean * rstd * ga;
  }
}

// ---- Kernel 1b: f32 -> bf16 convert (proj weights, one-time) ----
__global__ __launch_bounds__(256) void cvt_bf16(const float* __restrict__ src,
                                                u16* __restrict__ dst) {
  int i = blockIdx.x * 256 + threadIdx.x;
  const floatx4* s4 = (const floatx4*)src;
  floatx4 a = s4[2 * i], b = s4[2 * i + 1];
  V16 v;
#pragma unroll
  for (int j = 0; j < 4; ++j) { v.s[j] = f2bf(a[j]); v.s[4 + j] = f2bf(b[j]); }
  ((uintx4*)dst)[i] = v.u;
}

// ---- Kernel 1c: fold GN affine into QKV weights (per batch) ----
// wq2[bl][o][c] = bf16(w[o][c]*s[gb][c]); bq2[bl][o] = b_qkv[o] + sum_c w[o][c]*t[gb][c]
// grid (MQKV/16, Bc), block 256 (16 threads per o-row).
__global__ __launch_bounds__(256) void fold_w(const float* __restrict__ w_qkv,
    const float* __restrict__ b_qkv, const float* __restrict__ s_arr,
    const float* __restrict__ t_arr, u16* __restrict__ wq2,
    float* __restrict__ bq2, int b0) {
  int bl = blockIdx.y, gb = b0 + bl;
  int o = blockIdx.x * 16 + (threadIdx.x >> 4);
  int cth = threadIdx.x & 15;
  const float* w  = w_qkv + (size_t)o * C_;
  const float* sp = s_arr + (size_t)gb * C_;
  const float* tp = t_arr + (size_t)gb * C_;
  u16* wd = wq2 + ((size_t)bl * MQKV + o) * C_;
  V16 buf[4];
  float bt = 0.f;
#pragma unroll
  for (int i = 0; i < 8; ++i) {
    int c = cth * 32 + i * 4;
    floatx4 wv = *(const floatx4*)(w + c);
    floatx4 sv = *(const floatx4*)(sp + c);
    floatx4 tv = *(const floatx4*)(tp + c);
#pragma unroll
    for (int j = 0; j < 4; ++j) {
      buf[i >> 1].s[(i & 1) * 4 + j] = f2bf(wv[j] * sv[j]);
      bt += wv[j] * tv[j];
    }
  }
  uintx4* wo = (uintx4*)(wd + cth * 32);
#pragma unroll
  for (int i = 0; i < 4; ++i) wo[i] = buf[i].u;
#pragma unroll
  for (int off = 8; off > 0; off >>= 1) bt += __shfl_xor(bt, off);
  if (cth == 0) bq2[(size_t)bl * MQKV + o] = b_qkv[o] + bt;
}

// ------- Kernel 2: QKV GEMM 128x128, 2-phase dbuf, per-batch W', xtg-layout B ----
// out[bz][o][n] bf16 = sum_c W'[bz][o][c] * xtg[bz][g(c)][n][c%16] + bq2[bz][o]
__global__ __launch_bounds__(256) void gemm_qkv(
    const u16* __restrict__ Wq, const u16* __restrict__ Xg,
    const float* __restrict__ bq2, u16* __restrict__ outp, int M) {
  __shared__ alignas(16) u16 smem[2 * 2 * 128 * 64];   // [buf][As|Bs]; epilogue reuses
  int bz = blockIdx.z;
  int m0 = blockIdx.y * 128, n0 = blockIdx.x * 128;
  int tid = threadIdx.x, lane = tid & 63, wid = tid >> 6;
  int quad = lane >> 4, l15 = lane & 15;
  int wm = (wid >> 1) * 64, wn = (wid & 1) * 64;
  int sr = tid >> 3, sc = tid & 7;
  const u16* Ab = Wq + (size_t)bz * ((size_t)M * C_);
  const u16* Bb = Xg + (size_t)bz * ((size_t)C_ * N_);
  const float* bias = bq2 + (size_t)bz * M;
  floatx4 acc[4][4];
#pragma unroll
  for (int i = 0; i < 4; ++i)
#pragma unroll
    for (int j = 0; j < 4; ++j) acc[i][j] = (floatx4)0.f;

  auto stage = [&](int kt, int p) {
    u16* As = smem + p * 16384;
    u16* Bs = As + 8192;
#pragma unroll
    for (int i = 0; i < 4; ++i) {
      int rr = sr + i * 32;
      int cc = sc ^ (rr & 7);      // source-side pre-swizzle
      gld16(Ab + (size_t)(m0 + rr) * C_ + kt * 64 + cc * 8, &As[rr * 64 + sc * 8]);
      // B source in xtg layout: c = kt*64 + cc*8 -> g = kt*4 + (cc>>1), off = (cc&1)*8
      gld16(Bb + ((size_t)(kt * 4 + (cc >> 1)) * N_ + n0 + rr) * 16 + (cc & 1) * 8,
            &Bs[rr * 64 + sc * 8]);
    }
  };

  stage(0, 0);
  asm volatile("s_waitcnt vmcnt(0)" ::: "memory");
  __builtin_amdgcn_s_barrier();
  int cur = 0;
  for (int kt = 0; kt < 8; ++kt) {
    if (kt < 7) stage(kt + 1, cur ^ 1);
    const u16* As = smem + cur * 16384;
    const u16* Bs = As + 8192;
#pragma unroll
    for (int ks = 0; ks < 2; ++ks) {
      short8 af[4], bf8[4];
#pragma unroll
      for (int mi = 0; mi < 4; ++mi) {
        int row = wm + mi * 16 + l15;
        int kc = (ks * 4 + quad) ^ (row & 7);
        af[mi] = *(const short8*)&As[row * 64 + kc * 8];
      }
#pragma unroll
      for (int ni = 0; ni < 4; ++ni) {
        int row = wn + ni * 16 + l15;
        int kc = (ks * 4 + quad) ^ (row & 7);
        bf8[ni] = *(const short8*)&Bs[row * 64 + kc * 8];
      }
#pragma unroll
      for (int mi = 0; mi < 4; ++mi)
#pragma unroll
        for (int ni = 0; ni < 4; ++ni)
          acc[mi][ni] = __builtin_amdgcn_mfma_f32_16x16x32_bf16(af[mi], bf8[ni], acc[mi][ni], 0, 0, 0);
    }
    asm volatile("s_waitcnt vmcnt(0)" ::: "memory");
    __builtin_amdgcn_s_barrier();
    cur ^= 1;
  }
  // epilogue: LDS transpose -> 16B stores
  u16* E = smem;
#pragma unroll
  for (int mi = 0; mi < 4; ++mi)
#pragma unroll
    for (int ni = 0; ni < 4; ++ni)
#pragma unroll
      for (int r = 0; r < 4; ++r) {
        int row = wm + mi * 16 + quad * 4 + r;
        int col = wn + ni * 16 + l15;
        int ch = col >> 3;
        int cs = (ch & 8) | ((ch & 7) ^ (row & 7));
        E[row * 128 + cs * 8 + (col & 7)] = f2bf(acc[mi][ni][r] + bias[m0 + row]);
      }
  __syncthreads();
  int row = tid >> 1, half = tid & 1;
  u16* orow = outp + ((size_t)bz * M + m0 + row) * N_ + n0 + half * 64;
#pragma unroll
  for (int k = 0; k < 8; ++k) {
    int cs = (half * 8) | (k ^ (row & 7));
    *(uintx4*)(orow + k * 8) = *(const uintx4*)&E[row * 128 + cs * 8];
  }
}

// ------- Kernel 5: proj GEMM 128x128 (f32 out + bias + resid), B = [n][C] rows ----
__global__ __launch_bounds__(256) void gemm_bt(
    const u16* __restrict__ A, const u16* __restrict__ Bm,
    const float* __restrict__ bias, const float* __restrict__ resid,
    float* __restrict__ outv, int M) {
  __shared__ alignas(16) u16 smem[2 * 2 * 128 * 64];
  int bz = blockIdx.z;
  int m0 = blockIdx.y * 128, n0 = blockIdx.x * 128;
  int tid = threadIdx.x, lane = tid & 63, wid = tid >> 6;
  int quad = lane >> 4, l15 = lane & 15;
  int wm = (wid >> 1) * 64, wn = (wid & 1) * 64;
  int sr = tid >> 3, sc = tid & 7;
  const u16* Bb = Bm + (size_t)bz * ((size_t)N_ * C_);
  floatx4 acc[4][4];
#pragma unroll
  for (int i = 0; i < 4; ++i)
#pragma unroll
    for (int j = 0; j < 4; ++j) acc[i][j] = (floatx4)0.f;

  auto stage = [&](int kt, int p) {
    u16* As = smem + p * 16384;
    u16* Bs = As + 8192;
#pragma unroll
    for (int i = 0; i < 4; ++i) {
      int rr = sr + i * 32;
      int cc = sc ^ (rr & 7);
      gld16(A  + (size_t)(m0 + rr) * C_ + kt * 64 + cc * 8, &As[rr * 64 + sc * 8]);
      gld16(Bb + (size_t)(n0 + rr) * C_ + kt * 64 + cc * 8, &Bs[rr * 64 + sc * 8]);
    }
  };

  stage(0, 0);
  asm volatile("s_waitcnt vmcnt(0)" ::: "memory");
  __builtin_amdgcn_s_barrier();
  int cur = 0;
  for (int kt = 0; kt < 8; ++kt) {
    if (kt < 7) stage(kt + 1, cur ^ 1);
    const u16* As = smem + cur * 16384;
    const u16* Bs = As + 8192;
#pragma unroll
    for (int ks = 0; ks < 2; ++ks) {
      short8 af[4], bf8[4];
#pragma unroll
      for (int mi = 0; mi < 4; ++mi) {
        int row = wm + mi * 16 + l15;
        int kc = (ks * 4 + quad) ^ (row & 7);
        af[mi] = *(const short8*)&As[row * 64 + kc * 8];
      }
#pragma unroll
      for (int ni = 0; ni < 4; ++ni) {
        int row = wn + ni * 16 + l15;
        int kc = (ks * 4 + quad) ^ (row & 7);
        bf8[ni] = *(const short8*)&Bs[row * 64 + kc * 8];
      }
#pragma unroll
      for (int mi = 0; mi < 4; ++mi)
#pragma unroll
        for (int ni = 0; ni < 4; ++ni)
          acc[mi][ni] = __builtin_amdgcn_mfma_f32_16x16x32_bf16(af[mi], bf8[ni], acc[mi][ni], 0, 0, 0);
    }
    asm volatile("s_waitcnt vmcnt(0)" ::: "memory");
    __builtin_amdgcn_s_barrier();
    cur ^= 1;
  }
  // f32 epilogue: two passes of 64 rows x 128 cols, XOR-swizzled, float4 stores
  float* E = (float*)smem;
#pragma unroll
  for (int p = 0; p < 2; ++p) {
#pragma unroll
    for (int q = 0; q < 2; ++q)
#pragma unroll
      for (int ni = 0; ni < 4; ++ni)
#pragma unroll
        for (int r = 0; r < 4; ++r) {
          int mi = p * 2 + q;
          int lr = (wid >> 1) * 32 + q * 16 + quad * 4 + r;
          int col = wn + ni * 16 + l15;
          int ch = col >> 2;
          int cs = (ch & ~7) | ((ch & 7) ^ (lr & 7));
          E[lr * 128 + cs * 4 + (col & 3)] =
              acc[mi][ni][r] + bias[m0 + wm + mi * 16 + quad * 4 + r];
        }
    __syncthreads();
    int lr = tid >> 2, qt = tid & 3;
    int o = m0 + (lr >> 5) * 64 + p * 32 + (lr & 31);
    size_t obase = ((size_t)bz * M + o) * N_ + n0 + qt * 4;
#pragma unroll
    for (int k = 0; k < 8; ++k) {
      int ch = k * 4 + qt;
      int cs = (ch & ~7) | ((ch & 7) ^ (lr & 7));
      floatx4 v = *(const floatx4*)&E[lr * 128 + cs * 4];
      v += *(const floatx4*)(resid + obase + (size_t)k * 16);
      *(floatx4*)(outv + obase + (size_t)k * 16) = v;
    }
    if (p == 0) __syncthreads();
  }
}

// ---- Kernel 3a: partial S over an N-slice -> spart[p][bh][64][64] f32 ----
__global__ __launch_bounds__(256) void qk_partial(const u16* __restrict__ qkv,
    float* __restrict__ spart, int nbh) {
  int h = blockIdx.x, bz = blockIdx.y, p = blockIdx.z;
  const u16* qb = qkv + ((size_t)bz * MQKV + h * HD_) * N_;
  const u16* kb = qkv + ((size_t)bz * MQKV + C_ + h * HD_) * N_;
  int tid = threadIdx.x, lane = tid & 63, wid = tid >> 6;
  int quad = lane >> 4, l15 = lane & 15;
  floatx4 acc[4][4];
#pragma unroll
  for (int i = 0; i < 4; ++i)
#pragma unroll
    for (int j = 0; j < 4; ++j) acc[i][j] = (floatx4)0.f;

  for (int ks = 0; ks < 4; ++ks) {
    int n = p * 512 + wid * 128 + ks * 32 + quad * 8;
    short8 af[4], bf8[4];
#pragma unroll
    for (int mi = 0; mi < 4; ++mi)
      af[mi] = *(const short8*)(qb + (size_t)(mi * 16 + l15) * N_ + n);
#pragma unroll
    for (int ni = 0; ni < 4; ++ni)
      bf8[ni] = *(const short8*)(kb + (size_t)(ni * 16 + l15) * N_ + n);
#pragma unroll
    for (int mi = 0; mi < 4; ++mi)
#pragma unroll
      for (int ni = 0; ni < 4; ++ni)
        acc[mi][ni] = __builtin_amdgcn_mfma_f32_16x16x32_bf16(af[mi], bf8[ni], acc[mi][ni], 0, 0, 0);
  }
  __shared__ float S[64 * 68];
  for (int i = tid; i < 64 * 68; i += 256) S[i] = 0.f;
  __syncthreads();
#pragma unroll
  for (int mi = 0; mi < 4; ++mi)
#pragma unroll
    for (int ni = 0; ni < 4; ++ni)
#pragma unroll
      for (int r = 0; r < 4; ++r)
        atomicAdd(&S[(mi * 16 + quad * 4 + r) * 68 + ni * 16 + l15], acc[mi][ni][r]);
  __syncthreads();
  int bh = bz * NH_ + h;
  float* dst = spart + ((size_t)p * nbh + bh) * 4096 + tid * 16;
  int row = tid >> 2, c0 = (tid & 3) * 16;
#pragma unroll
  for (int j = 0; j < 4; ++j)
    *(floatx4*)(dst + j * 4) = *(const floatx4*)&S[row * 68 + c0 + j * 4];
}

// ---- Kernel 3b: sum partials + row softmax (one lane per row) ----
__global__ __launch_bounds__(64) void softmax_rows(const float* __restrict__ spart,
    float* __restrict__ attn, int nbh) {
  int bh = blockIdx.x, c = threadIdx.x;
  const float* sp = spart + (size_t)bh * 4096 + c * 64;
  floatx4 row4[16];
#pragma unroll
  for (int j = 0; j < 16; ++j) row4[j] = *(const floatx4*)(sp + j * 4);
#pragma unroll
  for (int p = 1; p < NSPL; ++p) {
    const float* spp = sp + (size_t)p * nbh * 4096;
#pragma unroll
    for (int j = 0; j < 16; ++j) row4[j] += *(const floatx4*)(spp + j * 4);
  }
  float mx = -1e30f;
#pragma unroll
  for (int j = 0; j < 16; ++j)
#pragma unroll
    for (int e = 0; e < 4; ++e) mx = fmaxf(mx, row4[j][e]);
  float sum = 0.f;
#pragma unroll
  for (int j = 0; j < 16; ++j)
#pragma unroll
    for (int e = 0; e < 4; ++e) {
      float ev = __expf((row4[j][e] - mx) * 0.125f);
      row4[j][e] = ev; sum += ev;
    }
  float inv = 1.f / sum;
  float* dst = attn + (size_t)bh * 4096 + c * 64;
#pragma unroll
  for (int j = 0; j < 16; ++j) *(floatx4*)(dst + j * 4) = row4[j] * inv;
}

// ------- Kernel 4: O = attn * v, output TRANSPOSED ot[bz][n][c] bf16 (c = h*64+hd) -----
__global__ __launch_bounds__(256) void pv_kernel(const float* __restrict__ attn,
    const u16* __restrict__ qkv, u16* __restrict__ ot) {
  int nt = blockIdx.x, h = blockIdx.y, bz = blockIdx.z;
  int n0 = nt * 256;
  const u16* vb = qkv + ((size_t)bz * MQKV + 2 * C_ + h * HD_) * N_;
  __shared__ alignas(16) u16 Ps[64 * 72];
  __shared__ alignas(16) u16 Vs[256 * 72];
  int tid = threadIdx.x, lane = tid & 63, wid = tid >> 6;
  int quad = lane >> 4, l15 = lane & 15;
  const float* ab = attn + (size_t)(bz * NH_ + h) * 4096;
#pragma unroll
  for (int i = 0; i < 16; ++i) {
    int idx = tid + i * 256;
    int row = idx >> 6, col = idx & 63;
    Ps[row * 72 + col] = f2bf(ab[idx]);
  }
#pragma unroll
  for (int i = 0; i < 8; ++i) {
    int l = tid + i * 256;
    int ch = l >> 5, n8 = (l & 31) * 8;
    V16 v; v.u = *(const uintx4*)(vb + (size_t)ch * N_ + n0 + n8);
    int chunk = ch >> 3, clo = ch & 7;
#pragma unroll
    for (int j = 0; j < 8; ++j) {
      int nl = n8 + j;
      Vs[nl * 72 + (chunk ^ ((nl >> 3) & 7)) * 8 + clo] = v.s[j];
    }
  }
  __syncthreads();
  floatx4 acc[4][4];
#pragma unroll
  for (int i = 0; i < 4; ++i)
#pragma unroll
    for (int j = 0; j < 4; ++j) acc[i][j] = (floatx4)0.f;
#pragma unroll
  for (int ks = 0; ks < 2; ++ks) {
    short8 af[4], bf8[4];
    int ko = ks * 32 + quad * 8;
#pragma unroll
    for (int mi = 0; mi < 4; ++mi)
      af[mi] = *(const short8*)&Ps[(mi * 16 + l15) * 72 + ko];
    int chunk = ks * 4 + quad;
#pragma unroll
    for (int ni = 0; ni < 4; ++ni) {
      int nl = wid * 64 + ni * 16 + l15;
      bf8[ni] = *(const short8*)&Vs[nl * 72 + (chunk ^ ((nl >> 3) & 7)) * 8];
    }
#pragma unroll
    for (int mi = 0; mi < 4; ++mi)
#pragma unroll
      for (int ni = 0; ni < 4; ++ni)
        acc[mi][ni] = __builtin_amdgcn_mfma_f32_16x16x32_bf16(af[mi], bf8[ni], acc[mi][ni], 0, 0, 0);
  }
  __syncthreads();
  u16* Ls = Vs;
#pragma unroll
  for (int mi = 0; mi < 4; ++mi)
#pragma unroll
    for (int ni = 0; ni < 4; ++ni)
#pragma unroll
      for (int r = 0; r < 4; ++r) {
        int n  = wid * 64 + ni * 16 + l15;
        int hd = mi * 16 + quad * 4 + r;
        Ls[n * 64 + (((hd >> 3) ^ (n & 7)) * 8) + (hd & 7)] = f2bf(acc[mi][ni][r]);
      }
  __syncthreads();
  uintx4* dst = (uintx4*)(ot + ((size_t)bz * N_ + n0 + tid) * C_ + h * HD_);
#pragma unroll
  for (int k = 0; k < 8; ++k) {
    int kc = k ^ (tid & 7);
    dst[k] = *(const uintx4*)&Ls[tid * 64 + kc * 8];
  }
}

extern "C" void kernel_launch(void* const* d_in, const int* in_sizes, int n_in,
                              void* d_out, int out_size, void* d_ws, size_t ws_size,
                              hipStream_t stream) {
  const float* x      = (const float*)d_in[0];
  const float* gamma  = (const float*)d_in[1];
  const float* beta   = (const float*)d_in[2];
  const float* w_qkv  = (const float*)d_in[3];
  const float* b_qkv  = (const float*)d_in[4];
  const float* w_proj = (const float*)d_in[5];
  const float* b_proj = (const float*)d_in[6];
  float* out = (float*)d_out;

  // ws: s[16*512] | t[16*512] f32 | wp bf16 | per-chunk: bq2 f32 | wq2 bf16 |
  //     attn f32 | xtg bf16 (aliased: spart, o_t) | qkv bf16
  const size_t fixed = (size_t)2 * B_ * C_ * 4 + (size_t)C_ * C_ * 2;
  const size_t per_batch = (size_t)MQKV * 4 + (size_t)MQKV * C_ * 2 +
                           (size_t)NH_ * 4096 * 4 + (size_t)C_ * N_ * 2 +
                           (size_t)MQKV * N_ * 2;
  int Bc = 16;
  while (Bc > 1 && fixed + (size_t)Bc * per_batch > ws_size) Bc >>= 1;

  float* s_arr = (float*)d_ws;
  float* t_arr = s_arr + B_ * C_;
  u16* wp   = (u16*)(t_arr + B_ * C_);
  float* bq2 = (float*)(wp + (size_t)C_ * C_);
  u16* wq2  = (u16*)(bq2 + (size_t)Bc * MQKV);
  float* attn = (float*)(wq2 + (size_t)Bc * MQKV * C_);
  u16* xtg  = (u16*)(attn + (size_t)Bc * NH_ * 4096);
  u16* qkv  = xtg + (size_t)Bc * C_ * N_;
  float* spart = (float*)xtg;   // xtg dead between QKV gemm and pv
  u16* ot = xtg;                // o_t reuses xtg region (pv writes after spart consumed)

  cvt_bf16<<<dim3(C_ * C_ / 2048), dim3(256), 0, stream>>>(w_proj, wp);

  for (int b0 = 0; b0 < B_; b0 += Bc) {
    int nbh = Bc * NH_;
    gn_stats_t<<<dim3(Bc * 32), dim3(256), 0, stream>>>(
        x + (size_t)b0 * C_ * N_, gamma, beta, s_arr, t_arr, xtg, b0);
    fold_w<<<dim3(MQKV / 16, Bc), dim3(256), 0, stream>>>(
        w_qkv, b_qkv, s_arr, t_arr, wq2, bq2, b0);
    gemm_qkv<<<dim3(32, 12, Bc), dim3(256), 0, stream>>>(
        wq2, xtg, bq2, qkv, MQKV);
    qk_partial<<<dim3(NH_, Bc, NSPL), dim3(256), 0, stream>>>(qkv, spart, nbh);
    softmax_rows<<<dim3(nbh), dim3(64), 0, stream>>>(spart, attn, nbh);
    pv_kernel<<<dim3(16, NH_, Bc), dim3(256), 0, stream>>>(attn, qkv, ot);
    gemm_bt<<<dim3(32, 4, Bc), dim3(256), 0, stream>>>(
        wp, ot, b_proj, x + (size_t)b0 * C_ * N_, out + (size_t)b0 * C_ * N_, C_);
  }
}

// Round 10
// 674.911 us; speedup vs baseline: 1.0327x; 1.0259x over previous
//
#include <hip/hip_runtime.h>

typedef unsigned short u16;
typedef __attribute__((ext_vector_type(8))) short short8;
typedef __attribute__((ext_vector_type(4))) float floatx4;
typedef __attribute__((ext_vector_type(4))) unsigned int uintx4;

#define B_    16
#define C_    512
#define N_    4096
#define NH_   8
#define HD_   64
#define MQKV  1536
#define NSPL  8

union V16 { uintx4 u; u16 s[8]; short8 h; };

__device__ inline u16 f2bf(float f) {
  union { float f; unsigned int i; } c; c.f = f;
  unsigned int i = c.i;
  return (u16)((i + 0x7FFFu + ((i >> 16) & 1u)) >> 16);
}

// async global->LDS, 16B per lane; LDS dest must be wave-uniform-base + lane*16
__device__ __forceinline__ void gld16(const u16* g, u16* l) {
  __builtin_amdgcn_global_load_lds(
      (const __attribute__((address_space(1))) unsigned int*)g,
      (__attribute__((address_space(3))) unsigned int*)l, 16, 0, 0);
}

// ---- Kernel 1: GroupNorm stats + transpose-cast in ONE x pass ----
// Writes xtg[bl][g][n][16] bf16 (raw x, NO affine — GN folded into weights),
// and s_arr/t_arr per (gb,c). grid (Bc*32), block 256.
__global__ __launch_bounds__(256) void gn_stats_t(const float* __restrict__ x,
    const float* __restrict__ gamma, const float* __restrict__ beta,
    float* __restrict__ s_arr, float* __restrict__ t_arr,
    u16* __restrict__ xtg, int b0) {
  __shared__ float T[16][256];   // 16 KB tile
  int bl = blockIdx.x >> 5, g = blockIdx.x & 31;
  int gb = b0 + bl;
  int tid = threadIdx.x;
  const float* xb = x + ((size_t)bl * C_ + g * 16) * N_;
  u16* xd = xtg + ((size_t)bl * 32 + g) * N_ * 16;
  float sum = 0.f, ssq = 0.f;
  for (int t8 = 0; t8 < 16; ++t8) {     // 16 n-tiles of 256
    int nb = t8 * 256;
#pragma unroll
    for (int i = 0; i < 4; ++i) {
      int idx = tid + i * 256;          // 0..1023
      int row = idx >> 6, col4 = idx & 63;
      floatx4 v = *(const floatx4*)(xb + (size_t)row * N_ + nb + col4 * 4);
#pragma unroll
      for (int j = 0; j < 4; ++j) { float f = v[j]; sum += f; ssq += f * f; }
      *(floatx4*)&T[row][col4 * 4] = v;
    }
    __syncthreads();
    V16 a, b;
#pragma unroll
    for (int j = 0; j < 8; ++j) a.s[j] = f2bf(T[j][tid]);
#pragma unroll
    for (int j = 0; j < 8; ++j) b.s[j] = f2bf(T[8 + j][tid]);
    uintx4* dst = (uintx4*)(xd + (size_t)(nb + tid) * 16);
    dst[0] = a.u; dst[1] = b.u;
    __syncthreads();
  }
#pragma unroll
  for (int off = 32; off > 0; off >>= 1) {
    sum += __shfl_down(sum, off);
    ssq += __shfl_down(ssq, off);
  }
  __shared__ float red[8];
  __shared__ float mv[2];
  int lane = tid & 63, wid = tid >> 6;
  if (lane == 0) { red[wid] = sum; red[wid + 4] = ssq; }
  __syncthreads();
  if (tid == 0) {
    float s = red[0] + red[1] + red[2] + red[3];
    float q = red[4] + red[5] + red[6] + red[7];
    float mean = s * (1.f / 65536.f);
    float var  = q * (1.f / 65536.f) - mean * mean;
    mv[0] = mean; mv[1] = rsqrtf(var + 1e-5f);
  }
  __syncthreads();
  if (tid < 16) {
    int c = g * 16 + tid;
    float ga = gamma[c], be = beta[c];
    float mean = mv[0], rstd = mv[1];
    s_arr[gb * C_ + c] = ga * rstd;
    t_arr[gb * C_ + c] = be - mean * rstd * ga;
  }
}

// ---- Kernel 1b: f32 -> bf16 convert (proj weights, one-time) ----
__global__ __launch_bounds__(256) void cvt_bf16(const float* __restrict__ src,
                                                u16* __restrict__ dst) {
  int i = blockIdx.x * 256 + threadIdx.x;
  const floatx4* s4 = (const floatx4*)src;
  floatx4 a = s4[2 * i], b = s4[2 * i + 1];
  V16 v;
#pragma unroll
  for (int j = 0; j < 4; ++j) { v.s[j] = f2bf(a[j]); v.s[4 + j] = f2bf(b[j]); }
  ((uintx4*)dst)[i] = v.u;
}

// ---- Kernel 1c: fold GN affine into QKV weights (per batch) ----
__global__ __launch_bounds__(256) void fold_w(const float* __restrict__ w_qkv,
    const float* __restrict__ b_qkv, const float* __restrict__ s_arr,
    const float* __restrict__ t_arr, u16* __restrict__ wq2,
    float* __restrict__ bq2, int b0) {
  int bl = blockIdx.y, gb = b0 + bl;
  int o = blockIdx.x * 16 + (threadIdx.x >> 4);
  int cth = threadIdx.x & 15;
  const float* w  = w_qkv + (size_t)o * C_;
  const float* sp = s_arr + (size_t)gb * C_;
  const float* tp = t_arr + (size_t)gb * C_;
  u16* wd = wq2 + ((size_t)bl * MQKV + o) * C_;
  V16 buf[4];
  float bt = 0.f;
#pragma unroll
  for (int i = 0; i < 8; ++i) {
    int c = cth * 32 + i * 4;
    floatx4 wv = *(const floatx4*)(w + c);
    floatx4 sv = *(const floatx4*)(sp + c);
    floatx4 tv = *(const floatx4*)(tp + c);
#pragma unroll
    for (int j = 0; j < 4; ++j) {
      buf[i >> 1].s[(i & 1) * 4 + j] = f2bf(wv[j] * sv[j]);
      bt += wv[j] * tv[j];
    }
  }
  uintx4* wo = (uintx4*)(wd + cth * 32);
#pragma unroll
  for (int i = 0; i < 4; ++i) wo[i] = buf[i].u;
#pragma unroll
  for (int off = 8; off > 0; off >>= 1) bt += __shfl_xor(bt, off);
  if (cth == 0) bq2[(size_t)bl * MQKV + o] = b_qkv[o] + bt;
}

// ------- Kernel 2: QKV GEMM 128x128, 2-phase dbuf. q,k rows -> [o][n]; v -> vt[n][c] ----
__global__ __launch_bounds__(256) void gemm_qkv(
    const u16* __restrict__ Wq, const u16* __restrict__ Xg,
    const float* __restrict__ bq2, u16* __restrict__ outp, int M) {
  __shared__ alignas(16) u16 smem[2 * 2 * 128 * 64];
  int bz = blockIdx.z;
  int m0 = blockIdx.y * 128, n0 = blockIdx.x * 128;
  int tid = threadIdx.x, lane = tid & 63, wid = tid >> 6;
  int quad = lane >> 4, l15 = lane & 15;
  int wm = (wid >> 1) * 64, wn = (wid & 1) * 64;
  int sr = tid >> 3, sc = tid & 7;
  const u16* Ab = Wq + (size_t)bz * ((size_t)M * C_);
  const u16* Bb = Xg + (size_t)bz * ((size_t)C_ * N_);
  const float* bias = bq2 + (size_t)bz * M;
  floatx4 acc[4][4];
#pragma unroll
  for (int i = 0; i < 4; ++i)
#pragma unroll
    for (int j = 0; j < 4; ++j) acc[i][j] = (floatx4)0.f;

  auto stage = [&](int kt, int p) {
    u16* As = smem + p * 16384;
    u16* Bs = As + 8192;
#pragma unroll
    for (int i = 0; i < 4; ++i) {
      int rr = sr + i * 32;
      int cc = sc ^ (rr & 7);
      gld16(Ab + (size_t)(m0 + rr) * C_ + kt * 64 + cc * 8, &As[rr * 64 + sc * 8]);
      gld16(Bb + ((size_t)(kt * 4 + (cc >> 1)) * N_ + n0 + rr) * 16 + (cc & 1) * 8,
            &Bs[rr * 64 + sc * 8]);
    }
  };

  stage(0, 0);
  asm volatile("s_waitcnt vmcnt(0)" ::: "memory");
  __builtin_amdgcn_s_barrier();
  int cur = 0;
  for (int kt = 0; kt < 8; ++kt) {
    if (kt < 7) stage(kt + 1, cur ^ 1);
    const u16* As = smem + cur * 16384;
    const u16* Bs = As + 8192;
#pragma unroll
    for (int ks = 0; ks < 2; ++ks) {
      short8 af[4], bf8[4];
#pragma unroll
      for (int mi = 0; mi < 4; ++mi) {
        int row = wm + mi * 16 + l15;
        int kc = (ks * 4 + quad) ^ (row & 7);
        af[mi] = *(const short8*)&As[row * 64 + kc * 8];
      }
#pragma unroll
      for (int ni = 0; ni < 4; ++ni) {
        int row = wn + ni * 16 + l15;
        int kc = (ks * 4 + quad) ^ (row & 7);
        bf8[ni] = *(const short8*)&Bs[row * 64 + kc * 8];
      }
#pragma unroll
      for (int mi = 0; mi < 4; ++mi)
#pragma unroll
        for (int ni = 0; ni < 4; ++ni)
          acc[mi][ni] = __builtin_amdgcn_mfma_f32_16x16x32_bf16(af[mi], bf8[ni], acc[mi][ni], 0, 0, 0);
    }
    asm volatile("s_waitcnt vmcnt(0)" ::: "memory");
    __builtin_amdgcn_s_barrier();
    cur ^= 1;
  }
  u16* E = smem;
  if (m0 < 2 * C_) {
    // q,k: row-major [o][n] store
#pragma unroll
    for (int mi = 0; mi < 4; ++mi)
#pragma unroll
      for (int ni = 0; ni < 4; ++ni)
#pragma unroll
        for (int r = 0; r < 4; ++r) {
          int row = wm + mi * 16 + quad * 4 + r;
          int col = wn + ni * 16 + l15;
          int ch = col >> 3;
          int cs = (ch & 8) | ((ch & 7) ^ (row & 7));
          E[row * 128 + cs * 8 + (col & 7)] = f2bf(acc[mi][ni][r] + bias[m0 + row]);
        }
    __syncthreads();
    int row = tid >> 1, half = tid & 1;
    u16* orow = outp + ((size_t)bz * M + m0 + row) * N_ + n0 + half * 64;
#pragma unroll
    for (int k = 0; k < 8; ++k) {
      int cs = (half * 8) | (k ^ (row & 7));
      *(uintx4*)(orow + k * 8) = *(const uintx4*)&E[row * 128 + cs * 8];
    }
  } else {
    // v: transposed store vt[n][c], c = o - 1024 (c-contig for proj B operand)
#pragma unroll
    for (int mi = 0; mi < 4; ++mi)
#pragma unroll
      for (int ni = 0; ni < 4; ++ni)
#pragma unroll
        for (int r = 0; r < 4; ++r) {
          int cl = wm + mi * 16 + quad * 4 + r;    // c-local
          int nl = wn + ni * 16 + l15;             // n-local
          int ch = cl >> 3;
          int cs = (ch & 8) | ((ch & 7) ^ (nl & 7));
          E[nl * 128 + cs * 8 + (cl & 7)] = f2bf(acc[mi][ni][r] + bias[m0 + cl]);
        }
    __syncthreads();
    u16* vt = outp + ((size_t)bz * M + 2 * C_) * N_;   // v region as [n][C_]
    int nl = tid >> 1, half = tid & 1;
    u16* drow = vt + (size_t)(n0 + nl) * C_ + (m0 - 2 * C_) + half * 64;
#pragma unroll
    for (int k = 0; k < 8; ++k) {
      int cs = (half * 8) | (k ^ (nl & 7));
      *(uintx4*)(drow + k * 8) = *(const uintx4*)&E[nl * 128 + cs * 8];
    }
  }
}

// ------- Kernel 5: proj GEMM 128x128 (f32 out + bias + resid), strided A/B ----
__global__ __launch_bounds__(256) void gemm_bt(
    const u16* __restrict__ A, const u16* __restrict__ Bm,
    const float* __restrict__ bias, const float* __restrict__ resid,
    float* __restrict__ outv, int M, size_t astride, size_t bstride) {
  __shared__ alignas(16) u16 smem[2 * 2 * 128 * 64];
  int bz = blockIdx.z;
  int m0 = blockIdx.y * 128, n0 = blockIdx.x * 128;
  int tid = threadIdx.x, lane = tid & 63, wid = tid >> 6;
  int quad = lane >> 4, l15 = lane & 15;
  int wm = (wid >> 1) * 64, wn = (wid & 1) * 64;
  int sr = tid >> 3, sc = tid & 7;
  const u16* Ab = A + (size_t)bz * astride;
  const u16* Bb = Bm + (size_t)bz * bstride;
  floatx4 acc[4][4];
#pragma unroll
  for (int i = 0; i < 4; ++i)
#pragma unroll
    for (int j = 0; j < 4; ++j) acc[i][j] = (floatx4)0.f;

  auto stage = [&](int kt, int p) {
    u16* As = smem + p * 16384;
    u16* Bs = As + 8192;
#pragma unroll
    for (int i = 0; i < 4; ++i) {
      int rr = sr + i * 32;
      int cc = sc ^ (rr & 7);
      gld16(Ab + (size_t)(m0 + rr) * C_ + kt * 64 + cc * 8, &As[rr * 64 + sc * 8]);
      gld16(Bb + (size_t)(n0 + rr) * C_ + kt * 64 + cc * 8, &Bs[rr * 64 + sc * 8]);
    }
  };

  stage(0, 0);
  asm volatile("s_waitcnt vmcnt(0)" ::: "memory");
  __builtin_amdgcn_s_barrier();
  int cur = 0;
  for (int kt = 0; kt < 8; ++kt) {
    if (kt < 7) stage(kt + 1, cur ^ 1);
    const u16* As = smem + cur * 16384;
    const u16* Bs = As + 8192;
#pragma unroll
    for (int ks = 0; ks < 2; ++ks) {
      short8 af[4], bf8[4];
#pragma unroll
      for (int mi = 0; mi < 4; ++mi) {
        int row = wm + mi * 16 + l15;
        int kc = (ks * 4 + quad) ^ (row & 7);
        af[mi] = *(const short8*)&As[row * 64 + kc * 8];
      }
#pragma unroll
      for (int ni = 0; ni < 4; ++ni) {
        int row = wn + ni * 16 + l15;
        int kc = (ks * 4 + quad) ^ (row & 7);
        bf8[ni] = *(const short8*)&Bs[row * 64 + kc * 8];
      }
#pragma unroll
      for (int mi = 0; mi < 4; ++mi)
#pragma unroll
        for (int ni = 0; ni < 4; ++ni)
          acc[mi][ni] = __builtin_amdgcn_mfma_f32_16x16x32_bf16(af[mi], bf8[ni], acc[mi][ni], 0, 0, 0);
    }
    asm volatile("s_waitcnt vmcnt(0)" ::: "memory");
    __builtin_amdgcn_s_barrier();
    cur ^= 1;
  }
  float* E = (float*)smem;
#pragma unroll
  for (int p = 0; p < 2; ++p) {
#pragma unroll
    for (int q = 0; q < 2; ++q)
#pragma unroll
      for (int ni = 0; ni < 4; ++ni)
#pragma unroll
        for (int r = 0; r < 4; ++r) {
          int mi = p * 2 + q;
          int lr = (wid >> 1) * 32 + q * 16 + quad * 4 + r;
          int col = wn + ni * 16 + l15;
          int ch = col >> 2;
          int cs = (ch & ~7) | ((ch & 7) ^ (lr & 7));
          E[lr * 128 + cs * 4 + (col & 3)] =
              acc[mi][ni][r] + bias[m0 + wm + mi * 16 + quad * 4 + r];
        }
    __syncthreads();
    int lr = tid >> 2, qt = tid & 3;
    int o = m0 + (lr >> 5) * 64 + p * 32 + (lr & 31);
    size_t obase = ((size_t)bz * M + o) * N_ + n0 + qt * 4;
#pragma unroll
    for (int k = 0; k < 8; ++k) {
      int ch = k * 4 + qt;
      int cs = (ch & ~7) | ((ch & 7) ^ (lr & 7));
      floatx4 v = *(const floatx4*)&E[lr * 128 + cs * 4];
      v += *(const floatx4*)(resid + obase + (size_t)k * 16);
      *(floatx4*)(outv + obase + (size_t)k * 16) = v;
    }
    if (p == 0) __syncthreads();
  }
}

// ---- Kernel 3a: partial S over an N-slice -> spart[p][bh][64][64] f32 ----
__global__ __launch_bounds__(256) void qk_partial(const u16* __restrict__ qkv,
    float* __restrict__ spart, int nbh) {
  int h = blockIdx.x, bz = blockIdx.y, p = blockIdx.z;
  const u16* qb = qkv + ((size_t)bz * MQKV + h * HD_) * N_;
  const u16* kb = qkv + ((size_t)bz * MQKV + C_ + h * HD_) * N_;
  int tid = threadIdx.x, lane = tid & 63, wid = tid >> 6;
  int quad = lane >> 4, l15 = lane & 15;
  floatx4 acc[4][4];
#pragma unroll
  for (int i = 0; i < 4; ++i)
#pragma unroll
    for (int j = 0; j < 4; ++j) acc[i][j] = (floatx4)0.f;

  for (int ks = 0; ks < 4; ++ks) {
    int n = p * 512 + wid * 128 + ks * 32 + quad * 8;
    short8 af[4], bf8[4];
#pragma unroll
    for (int mi = 0; mi < 4; ++mi)
      af[mi] = *(const short8*)(qb + (size_t)(mi * 16 + l15) * N_ + n);
#pragma unroll
    for (int ni = 0; ni < 4; ++ni)
      bf8[ni] = *(const short8*)(kb + (size_t)(ni * 16 + l15) * N_ + n);
#pragma unroll
    for (int mi = 0; mi < 4; ++mi)
#pragma unroll
      for (int ni = 0; ni < 4; ++ni)
        acc[mi][ni] = __builtin_amdgcn_mfma_f32_16x16x32_bf16(af[mi], bf8[ni], acc[mi][ni], 0, 0, 0);
  }
  __shared__ float S[64 * 68];
  for (int i = tid; i < 64 * 68; i += 256) S[i] = 0.f;
  __syncthreads();
#pragma unroll
  for (int mi = 0; mi < 4; ++mi)
#pragma unroll
    for (int ni = 0; ni < 4; ++ni)
#pragma unroll
      for (int r = 0; r < 4; ++r)
        atomicAdd(&S[(mi * 16 + quad * 4 + r) * 68 + ni * 16 + l15], acc[mi][ni][r]);
  __syncthreads();
  int bh = bz * NH_ + h;
  float* dst = spart + ((size_t)p * nbh + bh) * 4096 + tid * 16;
  int row = tid >> 2, c0 = (tid & 3) * 16;
#pragma unroll
  for (int j = 0; j < 4; ++j)
    *(floatx4*)(dst + j * 4) = *(const floatx4*)&S[row * 68 + c0 + j * 4];
}

// ---- Kernel 3b: sum partials + row softmax (one lane per row) ----
__global__ __launch_bounds__(64) void softmax_rows(const float* __restrict__ spart,
    float* __restrict__ attn, int nbh) {
  int bh = blockIdx.x, c = threadIdx.x;
  const float* sp = spart + (size_t)bh * 4096 + c * 64;
  floatx4 row4[16];
#pragma unroll
  for (int j = 0; j < 16; ++j) row4[j] = *(const floatx4*)(sp + j * 4);
#pragma unroll
  for (int p = 1; p < NSPL; ++p) {
    const float* spp = sp + (size_t)p * nbh * 4096;
#pragma unroll
    for (int j = 0; j < 16; ++j) row4[j] += *(const floatx4*)(spp + j * 4);
  }
  float mx = -1e30f;
#pragma unroll
  for (int j = 0; j < 16; ++j)
#pragma unroll
    for (int e = 0; e < 4; ++e) mx = fmaxf(mx, row4[j][e]);
  float sum = 0.f;
#pragma unroll
  for (int j = 0; j < 16; ++j)
#pragma unroll
    for (int e = 0; e < 4; ++e) {
      float ev = __expf((row4[j][e] - mx) * 0.125f);
      row4[j][e] = ev; sum += ev;
    }
  float inv = 1.f / sum;
  float* dst = attn + (size_t)bh * 4096 + c * 64;
#pragma unroll
  for (int j = 0; j < 16; ++j) *(floatx4*)(dst + j * 4) = row4[j] * inv;
}

// ---- Kernel 4: fold attn into proj weights: W2[bz][o][h64+d'] = sum_d wp[o][h64+d]*attn_h[d][d'] ----
// grid (NH_, Bc), block 256 (4 waves, each 128 o-rows).
__global__ __launch_bounds__(256) void fold_attn(const u16* __restrict__ wp,
    const float* __restrict__ attn, u16* __restrict__ W2) {
  __shared__ u16 AT[64 * 72];   // AT[d'][d] bf16 (transposed attn)
  int h = blockIdx.x, bz = blockIdx.y;
  int tid = threadIdx.x, lane = tid & 63, wid = tid >> 6;
  int quad = lane >> 4, l15 = lane & 15;
  const float* ab = attn + (size_t)(bz * NH_ + h) * 4096;
  {
    int d = tid >> 2, j0 = (tid & 3) * 16;
#pragma unroll
    for (int j4 = 0; j4 < 4; ++j4) {
      floatx4 v = *(const floatx4*)(ab + (size_t)d * 64 + j0 + j4 * 4);
#pragma unroll
      for (int j = 0; j < 4; ++j) AT[(j0 + j4 * 4 + j) * 72 + d] = f2bf(v[j]);
    }
  }
  __syncthreads();
  floatx4 acc[8][4];
#pragma unroll
  for (int i = 0; i < 8; ++i)
#pragma unroll
    for (int j = 0; j < 4; ++j) acc[i][j] = (floatx4)0.f;
#pragma unroll
  for (int ks = 0; ks < 2; ++ks) {
    short8 af[8], bf8[4];
#pragma unroll
    for (int mi = 0; mi < 8; ++mi) {
      int o = wid * 128 + mi * 16 + l15;
      af[mi] = *(const short8*)(wp + (size_t)o * C_ + h * HD_ + ks * 32 + quad * 8);
    }
#pragma unroll
    for (int ni = 0; ni < 4; ++ni)
      bf8[ni] = *(const short8*)&AT[(ni * 16 + l15) * 72 + ks * 32 + quad * 8];
#pragma unroll
    for (int mi = 0; mi < 8; ++mi)
#pragma unroll
      for (int ni = 0; ni < 4; ++ni)
        acc[mi][ni] = __builtin_amdgcn_mfma_f32_16x16x32_bf16(af[mi], bf8[ni], acc[mi][ni], 0, 0, 0);
  }
  u16* W2b = W2 + (size_t)bz * C_ * C_;
#pragma unroll
  for (int mi = 0; mi < 8; ++mi)
#pragma unroll
    for (int ni = 0; ni < 4; ++ni)
#pragma unroll
      for (int r = 0; r < 4; ++r) {
        int o  = wid * 128 + mi * 16 + quad * 4 + r;
        int dp = ni * 16 + l15;
        W2b[(size_t)o * C_ + h * HD_ + dp] = f2bf(acc[mi][ni][r]);
      }
}

extern "C" void kernel_launch(void* const* d_in, const int* in_sizes, int n_in,
                              void* d_out, int out_size, void* d_ws, size_t ws_size,
                              hipStream_t stream) {
  const float* x      = (const float*)d_in[0];
  const float* gamma  = (const float*)d_in[1];
  const float* beta   = (const float*)d_in[2];
  const float* w_qkv  = (const float*)d_in[3];
  const float* b_qkv  = (const float*)d_in[4];
  const float* w_proj = (const float*)d_in[5];
  const float* b_proj = (const float*)d_in[6];
  float* out = (float*)d_out;

  // ws: s|t f32 | wp bf16 | per-chunk: bq2 f32 | wq2 bf16 | attn f32 | W2 bf16 |
  //     xtg bf16 (alias spart) | qkv bf16 (v third = vt[n][c])
  const size_t fixed = (size_t)2 * B_ * C_ * 4 + (size_t)C_ * C_ * 2;
  const size_t per_batch = (size_t)MQKV * 4 + (size_t)MQKV * C_ * 2 +
                           (size_t)NH_ * 4096 * 4 + (size_t)C_ * C_ * 2 +
                           (size_t)C_ * N_ * 2 + (size_t)MQKV * N_ * 2;
  int Bc = 16;
  while (Bc > 1 && fixed + (size_t)Bc * per_batch > ws_size) Bc >>= 1;

  float* s_arr = (float*)d_ws;
  float* t_arr = s_arr + B_ * C_;
  u16* wp    = (u16*)(t_arr + B_ * C_);
  float* bq2 = (float*)(wp + (size_t)C_ * C_);
  u16* wq2   = (u16*)(bq2 + (size_t)Bc * MQKV);
  float* attn = (float*)(wq2 + (size_t)Bc * MQKV * C_);
  u16* W2    = (u16*)(attn + (size_t)Bc * NH_ * 4096);
  u16* xtg   = W2 + (size_t)Bc * C_ * C_;
  u16* qkv   = xtg + (size_t)Bc * C_ * N_;
  float* spart = (float*)xtg;   // xtg dead between QKV gemm and proj

  cvt_bf16<<<dim3(C_ * C_ / 2048), dim3(256), 0, stream>>>(w_proj, wp);

  for (int b0 = 0; b0 < B_; b0 += Bc) {
    int nbh = Bc * NH_;
    gn_stats_t<<<dim3(Bc * 32), dim3(256), 0, stream>>>(
        x + (size_t)b0 * C_ * N_, gamma, beta, s_arr, t_arr, xtg, b0);
    fold_w<<<dim3(MQKV / 16, Bc), dim3(256), 0, stream>>>(
        w_qkv, b_qkv, s_arr, t_arr, wq2, bq2, b0);
    gemm_qkv<<<dim3(32, 12, Bc), dim3(256), 0, stream>>>(
        wq2, xtg, bq2, qkv, MQKV);
    qk_partial<<<dim3(NH_, Bc, NSPL), dim3(256), 0, stream>>>(qkv, spart, nbh);
    softmax_rows<<<dim3(nbh), dim3(64), 0, stream>>>(spart, attn, nbh);
    fold_attn<<<dim3(NH_, Bc), dim3(256), 0, stream>>>(wp, attn, W2);
    // proj: out = W2 * vt^T + b_proj + x   (vt = v region of qkv, [n][C] c-contig)
    gemm_bt<<<dim3(32, 4, Bc), dim3(256), 0, stream>>>(
        W2, qkv + (size_t)2 * C_ * N_, b_proj, x + (size_t)b0 * C_ * N_,
        out + (size_t)b0 * C_ * N_, C_, (size_t)C_ * C_, (size_t)MQKV * N_);
  }
}